// Round 12
// baseline (193.663 us; speedup 1.0000x reference)
//
#include <hip/hip_runtime.h>
#include <hip/hip_bf16.h>
#include <stdint.h>

// Problem constants (CompressedKVAttention_11708080848911)
#define Bc    4
#define Hc    32
#define HKVc  8
#define QLc   16
#define KVc   8192
#define Dc    128
#define NREPc 4   // H / HKV

typedef _Float16 f16x8 __attribute__((ext_vector_type(8)));
typedef float f32x4  __attribute__((ext_vector_type(4)));
typedef int   i32x4  __attribute__((ext_vector_type(4)));
typedef uint32_t u32x2 __attribute__((ext_vector_type(2)));

// Pack two sign-extended-int8 dwords into one half2 = (x0+1152, x1+1152).
// fp16 0x6400|u = 1024+u (u in [0,255] exact); u = byte^0x80 = x+128.
__device__ __forceinline__ uint32_t pk1152(int x0, int x1) {
  return (__builtin_amdgcn_perm((uint32_t)x1, (uint32_t)x0, 0x05040100u)
          & 0x00FF00FFu) ^ 0x64806480u;
}

// ---------------------------------------------------------------------------
// Phase 1: per-(bg,split,head) flash partials. KV caches arrive as INT32.
// R11: ONE WAVE PER BLOCK (64 threads, 8192 blocks). Findings driving this:
//  - Warm replays read K/V entirely from L2/L3 (FETCH~0) yet run the same
//    112-122us as cold -> NOT bandwidth/HBM-latency bound; bound by exposed
//    on-chip latency x low concurrency.
//  - Occupancy pinned at ~6.4 waves/CU across R6-R10 regardless of LDS/VGPR/
//    barriers (~3x below static caps). This round tests whether the cap is
//    per-BLOCK (would serialize badly here -> decisive) or per-wave (then
//    1-wave blocks give the scheduler maximal packing freedom).
//  - __syncthreads drains vmcnt(0) (m97) so cross-barrier prefetch never
//    overlapped in R7-R9; this design has ZERO barriers.
// Per wave: R10's private path -- K per-lane direct global->frag loads
// (fp16 pk1152 dequant), V staged to a private LDS slice (transposed [d][t],
// token bits 3..4 XOR (d>>4)&3, rows padded to 80B), P transposed via LDS,
// swapped-max online softmax, P''=p*vs*1024 fp16.
// 4 consecutive bids share the same (bg,split) K/V chunk -> L2/L3 locality.
// ---------------------------------------------------------------------------
__global__ __launch_bounds__(64) void attn_partial(
    const float* __restrict__ q, const int* __restrict__ kc,
    const int* __restrict__ vc,
    const float* __restrict__ ksc, const float* __restrict__ kzr,
    const float* __restrict__ vsc, const float* __restrict__ vzr,
    float* __restrict__ ws_acc, float* __restrict__ ws_m,
    float* __restrict__ ws_l, int nsplit)
{
  __shared__ __align__(16) unsigned short Vlds[128][40]; // 10.0 KB
  __shared__ __align__(16) unsigned short Plds[16][40];  // 1.25 KB

  const int bid   = blockIdx.x;
  const int head  = bid & 3;               // 4 consecutive bids share K/V
  const int sid   = bid >> 2;
  const int split = sid % nsplit;
  const int bg    = sid / nsplit;          // 0..31  (= b*HKV + g)
  const int chunk = KVc / nsplit;
  const int t_begin = split * chunk;
  const int nt    = chunk >> 5;            // 32-token tiles

  const int lane = threadIdx.x & 63;
  const int l15  = lane & 15;
  const int lg   = lane >> 4;              // 0..3

  const int b = bg >> 3, g = bg & 7;
  const int h = (g << 2) + head;           // this wave's query head

  // ---- Q fragments (fp16) + per-row sum of fp16-rounded Q ----
  f16x8 qa[4];
  float qsum = 0.f;
  const float* qrow = q + ((size_t)((b * Hc + h) * QLc + l15)) * Dc;
#pragma unroll
  for (int ks = 0; ks < 4; ++ks) {
    const f32x4* qv = (const f32x4*)(qrow + ks * 32 + (lg << 3));
    f32x4 qlo = qv[0], qhi = qv[1];
    f16x8 f;
#pragma unroll
    for (int j = 0; j < 4; ++j) {
      f[j]     = (_Float16)qlo[j];
      f[4 + j] = (_Float16)qhi[j];
      qsum += (float)f[j] + (float)f[4 + j];   // post-rounding values
    }
    qa[ks] = f;
  }
  qsum += __shfl_xor(qsum, 16);
  qsum += __shfl_xor(qsum, 32);            // every lane: qsum of row (lane&15)
  float qsumc[4];                          // re-map to C-layout rows 4*lg+j
#pragma unroll
  for (int j = 0; j < 4; ++j) qsumc[j] = __shfl(qsum, (lg << 2) + j);

  const float QK_SCALE = 0.088388347648f * 1.44269504089f; // d^-1/2 * log2(e)

  float m[4], ell[4], corr[4];
  f32x4 acc[8];
#pragma unroll
  for (int j = 0; j < 4; ++j) { m[j] = -1e30f; ell[j] = 0.f; corr[j] = 0.f; }
#pragma unroll
  for (int dt = 0; dt < 8; ++dt) acc[dt] = (f32x4){0.f, 0.f, 0.f, 0.f};

  const int*   kb   = kc  + (size_t)bg * KVc * Dc;
  const int*   vbp  = vc  + (size_t)bg * KVc * Dc;
  const float* kscb = ksc + (size_t)bg * KVc;
  const float* kzrb = kzr + (size_t)bg * KVc;
  const float* vscb = vsc + (size_t)bg * KVc;
  const float* vzrb = vzr + (size_t)bg * KVc;

  const int vswz = ((l15 >> 2) & 3) << 3;  // XOR on token bits 3..4

  for (int it = 0; it < nt; ++it) {
    const int t0 = t_begin + (it << 5);
    const int tA = t0 + l15, tB = tA + 16;

    // scales (coalesced 64B over l15 lanes; issued early, used mid-tile)
    const float ksA = kscb[tA], kzA = kzrb[tA], vsA = vscb[tA], vzA = vzrb[tA];
    const float ksB = kscb[tB], kzB = kzrb[tB], vsB = vscb[tB], vzB = vzrb[tB];

    // ---- QK half A: 8 dwordx4 direct loads -> frags -> MFMA ----
    f32x4 scA = (f32x4){0.f, 0.f, 0.f, 0.f};
    f32x4 scB = (f32x4){0.f, 0.f, 0.f, 0.f};
    {
      const int* kp = kb + (size_t)tA * Dc;
      i32x4 ka0 = *(const i32x4*)(kp + 0   + (lg << 3));
      i32x4 ka1 = *(const i32x4*)(kp + 4   + (lg << 3));
      i32x4 ka2 = *(const i32x4*)(kp + 32  + (lg << 3));
      i32x4 ka3 = *(const i32x4*)(kp + 36  + (lg << 3));
      i32x4 ka4 = *(const i32x4*)(kp + 64  + (lg << 3));
      i32x4 ka5 = *(const i32x4*)(kp + 68  + (lg << 3));
      i32x4 ka6 = *(const i32x4*)(kp + 96  + (lg << 3));
      i32x4 ka7 = *(const i32x4*)(kp + 100 + (lg << 3));
      i32x4 kw;
      kw[0] = (int)pk1152(ka0[0], ka0[1]); kw[1] = (int)pk1152(ka0[2], ka0[3]);
      kw[2] = (int)pk1152(ka1[0], ka1[1]); kw[3] = (int)pk1152(ka1[2], ka1[3]);
      scA = __builtin_amdgcn_mfma_f32_16x16x32_f16(qa[0], *(const f16x8*)&kw, scA, 0, 0, 0);
      kw[0] = (int)pk1152(ka2[0], ka2[1]); kw[1] = (int)pk1152(ka2[2], ka2[3]);
      kw[2] = (int)pk1152(ka3[0], ka3[1]); kw[3] = (int)pk1152(ka3[2], ka3[3]);
      scA = __builtin_amdgcn_mfma_f32_16x16x32_f16(qa[1], *(const f16x8*)&kw, scA, 0, 0, 0);
      kw[0] = (int)pk1152(ka4[0], ka4[1]); kw[1] = (int)pk1152(ka4[2], ka4[3]);
      kw[2] = (int)pk1152(ka5[0], ka5[1]); kw[3] = (int)pk1152(ka5[2], ka5[3]);
      scA = __builtin_amdgcn_mfma_f32_16x16x32_f16(qa[2], *(const f16x8*)&kw, scA, 0, 0, 0);
      kw[0] = (int)pk1152(ka6[0], ka6[1]); kw[1] = (int)pk1152(ka6[2], ka6[3]);
      kw[2] = (int)pk1152(ka7[0], ka7[1]); kw[3] = (int)pk1152(ka7[2], ka7[3]);
      scA = __builtin_amdgcn_mfma_f32_16x16x32_f16(qa[3], *(const f16x8*)&kw, scA, 0, 0, 0);
    }
    // ---- QK half B ----
    {
      const int* kp = kb + (size_t)tB * Dc;
      i32x4 ka0 = *(const i32x4*)(kp + 0   + (lg << 3));
      i32x4 ka1 = *(const i32x4*)(kp + 4   + (lg << 3));
      i32x4 ka2 = *(const i32x4*)(kp + 32  + (lg << 3));
      i32x4 ka3 = *(const i32x4*)(kp + 36  + (lg << 3));
      i32x4 ka4 = *(const i32x4*)(kp + 64  + (lg << 3));
      i32x4 ka5 = *(const i32x4*)(kp + 68  + (lg << 3));
      i32x4 ka6 = *(const i32x4*)(kp + 96  + (lg << 3));
      i32x4 ka7 = *(const i32x4*)(kp + 100 + (lg << 3));
      i32x4 kw;
      kw[0] = (int)pk1152(ka0[0], ka0[1]); kw[1] = (int)pk1152(ka0[2], ka0[3]);
      kw[2] = (int)pk1152(ka1[0], ka1[1]); kw[3] = (int)pk1152(ka1[2], ka1[3]);
      scB = __builtin_amdgcn_mfma_f32_16x16x32_f16(qa[0], *(const f16x8*)&kw, scB, 0, 0, 0);
      kw[0] = (int)pk1152(ka2[0], ka2[1]); kw[1] = (int)pk1152(ka2[2], ka2[3]);
      kw[2] = (int)pk1152(ka3[0], ka3[1]); kw[3] = (int)pk1152(ka3[2], ka3[3]);
      scB = __builtin_amdgcn_mfma_f32_16x16x32_f16(qa[1], *(const f16x8*)&kw, scB, 0, 0, 0);
      kw[0] = (int)pk1152(ka4[0], ka4[1]); kw[1] = (int)pk1152(ka4[2], ka4[3]);
      kw[2] = (int)pk1152(ka5[0], ka5[1]); kw[3] = (int)pk1152(ka5[2], ka5[3]);
      scB = __builtin_amdgcn_mfma_f32_16x16x32_f16(qa[2], *(const f16x8*)&kw, scB, 0, 0, 0);
      kw[0] = (int)pk1152(ka6[0], ka6[1]); kw[1] = (int)pk1152(ka6[2], ka6[3]);
      kw[2] = (int)pk1152(ka7[0], ka7[1]); kw[3] = (int)pk1152(ka7[2], ka7[3]);
      scB = __builtin_amdgcn_mfma_f32_16x16x32_f16(qa[3], *(const f16x8*)&kw, scB, 0, 0, 0);
    }

    float s8[2][4];
    const float sclA = ksA * QK_SCALE, kzpA = kzA + 1152.f;
    const float sclB = ksB * QK_SCALE, kzpB = kzB + 1152.f;
#pragma unroll
    for (int j = 0; j < 4; ++j) {
      s8[0][j] = sclA * (scA[j] - kzpA * qsumc[j]);
      s8[1][j] = sclB * (scB[j] - kzpB * qsumc[j]);
    }

    // one max update + rescale per 32-token tile
    float tm[4];
#pragma unroll
    for (int j = 0; j < 4; ++j) {
      tm[j] = fmaxf(s8[0][j], s8[1][j]);
      tm[j] = fmaxf(tm[j], __shfl_xor(tm[j], 1));
      tm[j] = fmaxf(tm[j], __shfl_xor(tm[j], 2));
      tm[j] = fmaxf(tm[j], __shfl_xor(tm[j], 4));
      tm[j] = fmaxf(tm[j], __shfl_xor(tm[j], 8));
    }
    bool need = false;
    float cf[4];
#pragma unroll
    for (int j = 0; j < 4; ++j) {
      float nm = fmaxf(m[j], tm[j]);
      cf[j] = exp2f(m[j] - nm);
      need = need || (tm[j] > m[j]);
      m[j] = nm;
    }
    if (__any(need)) {
#pragma unroll
      for (int j = 0; j < 4; ++j) { ell[j] *= cf[j]; corr[j] *= cf[j]; }
#pragma unroll
      for (int dt = 0; dt < 8; ++dt)
#pragma unroll
        for (int j = 0; j < 4; ++j) acc[dt][j] *= cf[j];
    }

    // P" = p*vs*1024 (fp16); corr uses ROUNDED P"; write Plds
    const float vsA1k = vsA * 1024.f, vzpA = vzA + 1152.f;
    const float vsB1k = vsB * 1024.f, vzpB = vzB + 1152.f;
#pragma unroll
    for (int j = 0; j < 4; ++j) {
      float pA = exp2f(s8[0][j] - m[j]);
      float pB = exp2f(s8[1][j] - m[j]);
      ell[j] += pA + pB;
      union { _Float16 hh; unsigned short u; } ca, cb;
      ca.hh = (_Float16)(pA * vsA1k);
      cb.hh = (_Float16)(pB * vsB1k);
      corr[j] += (float)ca.hh * vzpA + (float)cb.hh * vzpB;
      Plds[(lg << 2) + j][l15]      = ca.u;
      Plds[(lg << 2) + j][16 + l15] = cb.u;
    }

    // ---- V staging (4 chunks, 1-deep load pipeline) ----
    {
      i32x4 va0, va1, va2, va3, vb0, vb1, vb2, vb3;
      {
        const int* vs0 = vbp + (size_t)(t0 + (lg << 2)) * Dc + (l15 << 2);
        va0 = *(const i32x4*)(vs0);
        va1 = *(const i32x4*)(vs0 + Dc);
        va2 = *(const i32x4*)(vs0 + 2 * Dc);
        va3 = *(const i32x4*)(vs0 + 3 * Dc);
      }
#pragma unroll
      for (int c = 0; c < 4; ++c) {
        if (c + 1 < 4) {
          const int cn = c + 1;
          const int* vsn = vbp + (size_t)(t0 + ((cn & 1) << 4) + (lg << 2)) * Dc
                         + ((cn >> 1) << 6) + (l15 << 2);
          vb0 = *(const i32x4*)(vsn);
          vb1 = *(const i32x4*)(vsn + Dc);
          vb2 = *(const i32x4*)(vsn + 2 * Dc);
          vb3 = *(const i32x4*)(vsn + 3 * Dc);
        }
        const int colb = (((c & 1) << 4) + (lg << 2)) ^ vswz;
        const int dbc  = ((c >> 1) << 6) + (l15 << 2);
#pragma unroll
        for (int j = 0; j < 4; ++j) {
          u32x2 pk;
          pk[0] = pk1152(va0[j], va1[j]);
          pk[1] = pk1152(va2[j], va3[j]);
          *(u32x2*)&Vlds[dbc + j][colb] = pk;
        }
        va0 = vb0; va1 = vb1; va2 = vb2; va3 = vb3;
      }
    }

    // ---- PV for these 32 tokens (wave-private LDS; lgkmcnt orders W->R) ----
    f16x8 pa = *(const f16x8*)&Plds[l15][lg << 3];
#pragma unroll
    for (int dt = 0; dt < 8; ++dt) {
      f16x8 vbf = *(const f16x8*)
          &Vlds[(dt << 4) + l15][(lg ^ (dt & 3)) << 3];
      acc[dt] = __builtin_amdgcn_mfma_f32_16x16x32_f16(pa, vbf, acc[dt], 0, 0, 0);
    }
  }

  // ---- final lane reductions over token slots ----
#pragma unroll
  for (int j = 0; j < 4; ++j) {
    ell[j] += __shfl_xor(ell[j], 1);  ell[j] += __shfl_xor(ell[j], 2);
    ell[j] += __shfl_xor(ell[j], 4);  ell[j] += __shfl_xor(ell[j], 8);
    corr[j] += __shfl_xor(corr[j], 1); corr[j] += __shfl_xor(corr[j], 2);
    corr[j] += __shfl_xor(corr[j], 4); corr[j] += __shfl_xor(corr[j], 8);
  }

  const size_t pbase = ((size_t)bg * nsplit + split) * 64;
  const float inv1k = 0.0009765625f;       // 1/1024 (undo P" scaling)
#pragma unroll
  for (int dt = 0; dt < 8; ++dt)
#pragma unroll
    for (int j = 0; j < 4; ++j) {
      int row = (head << 4) + (lg << 2) + j;
      int d   = (dt << 4) + l15;
      ws_acc[(pbase + row) * Dc + d] = (acc[dt][j] - corr[j]) * inv1k;
    }
  if (l15 == 0) {
#pragma unroll
    for (int j = 0; j < 4; ++j) {
      int row = (head << 4) + (lg << 2) + j;
      ws_m[pbase + row] = m[j];
      ws_l[pbase + row] = ell[j];
    }
  }
}

// ---------------------------------------------------------------------------
// Phase 2: flash-combine partials and normalize. One block per (bg,row).
// ---------------------------------------------------------------------------
__global__ __launch_bounds__(128) void attn_combine(
    const float* __restrict__ ws_acc, const float* __restrict__ ws_m,
    const float* __restrict__ ws_l, float* __restrict__ out, int nsplit)
{
  const int r   = blockIdx.x;      // 0 .. 32*64-1
  const int bg  = r >> 6;
  const int row = r & 63;
  const int d   = threadIdx.x;     // 0..127

  float M = -1e30f;
#pragma unroll 4
  for (int i = 0; i < nsplit; ++i)
    M = fmaxf(M, ws_m[((size_t)bg * nsplit + i) * 64 + row]);
  float L = 0.f, o = 0.f;
#pragma unroll 4
  for (int i = 0; i < nsplit; ++i) {
    size_t pb = ((size_t)bg * nsplit + i) * 64 + row;
    float w = exp2f(ws_m[pb] - M);
    L += ws_l[pb] * w;
    o += ws_acc[pb * Dc + d] * w;
  }
  const int b = bg >> 3, g = bg & 7;
  const int rep = row >> 4, qq = row & 15;
  out[(((size_t)(b * Hc + g * NREPc + rep)) * QLc + qq) * Dc + d] = o / L;
}

extern "C" void kernel_launch(void* const* d_in, const int* in_sizes, int n_in,
                              void* d_out, int out_size, void* d_ws,
                              size_t ws_size, hipStream_t stream) {
  const float* q   = (const float*)d_in[0];
  const int*   kc  = (const int*)d_in[1];   // int8 values promoted to int32
  const int*   vc  = (const int*)d_in[2];
  const float* ksc = (const float*)d_in[3];
  const float* kzr = (const float*)d_in[4];
  const float* vsc = (const float*)d_in[5];
  const float* vzr = (const float*)d_in[6];
  float* out = (float*)d_out;

  int nsplit = 64;                         // fallback if ws small
  while (nsplit > 1) {
    size_t need = (size_t)32 * nsplit * 64 * (Dc + 2) * sizeof(float);
    if (need <= ws_size) break;
    nsplit >>= 1;
  }
  float* ws_acc = (float*)d_ws;                             // [32,ns,64,128]
  float* ws_m   = ws_acc + (size_t)32 * nsplit * 64 * Dc;   // [32,ns,64]
  float* ws_l   = ws_m   + (size_t)32 * nsplit * 64;        // [32,ns,64]

  attn_partial<<<dim3(32 * nsplit * 4), dim3(64), 0, stream>>>(
      q, kc, vc, ksc, kzr, vsc, vzr, ws_acc, ws_m, ws_l, nsplit);
  attn_combine<<<dim3(32 * 64), dim3(128), 0, stream>>>(
      ws_acc, ws_m, ws_l, out, nsplit);
}

// Round 13
// 108.544 us; speedup vs baseline: 1.7842x; 1.7842x over previous
//
#include <hip/hip_runtime.h>
#include <hip/hip_bf16.h>
#include <stdint.h>

// Problem constants (CompressedKVAttention_11708080848911)
#define Bc    4
#define Hc    32
#define HKVc  8
#define QLc   16
#define KVc   8192
#define Dc    128
#define NREPc 4   // H / HKV

typedef _Float16 f16x8 __attribute__((ext_vector_type(8)));
typedef float f32x4  __attribute__((ext_vector_type(4)));
typedef int   i32x4  __attribute__((ext_vector_type(4)));
typedef uint32_t u32x2 __attribute__((ext_vector_type(2)));

// Pack two sign-extended-int8 dwords into one half2 = (x0+1152, x1+1152).
// fp16 0x6400|u = 1024+u (u in [0,255] exact); u = byte^0x80 = x+128.
__device__ __forceinline__ uint32_t pk1152(int x0, int x1) {
  return (__builtin_amdgcn_perm((uint32_t)x1, (uint32_t)x0, 0x05040100u)
          & 0x00FF00FFu) ^ 0x64806480u;
}

// Raw barrier WITHOUT the vmcnt(0) drain __syncthreads carries (m97).
// lgkmcnt(0): this wave's LDS writes are committed before it signals.
// Execution sync makes cross-wave LDS reads/writes safe; vmem loads
// (per-wave register prefetch) STAY IN FLIGHT across the barrier -- their
// counted vmcnt wait lands at first use, one full compute phase later.
#define BAR() do {                                            \
    asm volatile("s_waitcnt lgkmcnt(0)" ::: "memory");        \
    __builtin_amdgcn_sched_barrier(0);                        \
    __builtin_amdgcn_s_barrier();                             \
  } while (0)

// ---------------------------------------------------------------------------
// Phase 1: per-(b,g,split) flash partials. KV caches arrive as INT32.
// R12: R9 structure (112us) + TWO changes:
//  (1) raw s_barrier + lgkmcnt(0) instead of __syncthreads: removes the
//      vmcnt(0) drain that forced every prefetched load to COMPLETE at every
//      barrier (this capped pipeline depth at 0 across R6-R9; warm replays
//      at L2/L3 speed were identical to cold -> ~2-4K cy loaded latency was
//      exposed per tile).
//  (2) scale loads (ks/kz/vs/vz) are loop-carried registers prefetched one
//      tile ahead in the locked section (they were 4 dependent ~2K-cy loads
//      sitting on the compute critical path).
// Everything else = R9: 4 waves, fp16 pk1152 dequant, K LDS col^((row&7)<<3)
// swizzle both sides, V [d][t] transposed w/ token-bit XOR swizzle + 40-col
// pad, single-buffered K/V, loads for tile it+2 issued in locked(it),
// swapped-max online softmax once per 32-token tile, P''=p*vs*1024.
// ---------------------------------------------------------------------------
__global__ __launch_bounds__(256) void attn_partial(
    const float* __restrict__ q, const int* __restrict__ kc,
    const int* __restrict__ vc,
    const float* __restrict__ ksc, const float* __restrict__ kzr,
    const float* __restrict__ vsc, const float* __restrict__ vzr,
    float* __restrict__ ws_acc, float* __restrict__ ws_m,
    float* __restrict__ ws_l, int nsplit)
{
  __shared__ __align__(16) unsigned short Klds[32][128];   // fp16 bits, 8 KB
  __shared__ __align__(16) unsigned short Vlds[128][40];   // fp16 bits, 10 KB
  __shared__ __align__(16) unsigned short Plds[4][16][40]; // fp16 bits, 5 KB

  const int bid   = blockIdx.x;
  const int split = bid % nsplit;
  const int bg    = bid / nsplit;          // 0..31  (= b*HKV + g)
  const int chunk = KVc / nsplit;
  const int t_begin = split * chunk;
  const int nt    = chunk >> 5;            // 32-token tiles

  const int tid  = threadIdx.x;
  const int wave = tid >> 6;
  const int lane = tid & 63;
  const int l15  = lane & 15;
  const int lg   = lane >> 4;              // 0..3

  const int b = bg >> 3, g = bg & 7;
  const int h = (g << 2) + wave;           // this wave's query head

  // ---- Q fragments (fp16) + per-row sum of fp16-rounded Q ----
  f16x8 qa[4];
  float qsum = 0.f;
  const float* qrow = q + ((size_t)((b * Hc + h) * QLc + l15)) * Dc;
#pragma unroll
  for (int ks = 0; ks < 4; ++ks) {
    const f32x4* qv = (const f32x4*)(qrow + ks * 32 + (lg << 3));
    f32x4 qlo = qv[0], qhi = qv[1];
    f16x8 f;
#pragma unroll
    for (int j = 0; j < 4; ++j) {
      f[j]     = (_Float16)qlo[j];
      f[4 + j] = (_Float16)qhi[j];
      qsum += (float)f[j] + (float)f[4 + j];   // post-rounding values
    }
    qa[ks] = f;
  }
  qsum += __shfl_xor(qsum, 16);
  qsum += __shfl_xor(qsum, 32);            // every lane: qsum of row (lane&15)
  float qsumc[4];                          // re-map to C-layout rows 4*lg+j
#pragma unroll
  for (int j = 0; j < 4; ++j) qsumc[j] = __shfl(qsum, (lg << 2) + j);

  const float QK_SCALE = 0.088388347648f * 1.44269504089f; // d^-1/2 * log2(e)

  float m[4], ell[4], corr[4];
  f32x4 acc[8];
#pragma unroll
  for (int j = 0; j < 4; ++j) { m[j] = -1e30f; ell[j] = 0.f; corr[j] = 0.f; }
#pragma unroll
  for (int dt = 0; dt < 8; ++dt) acc[dt] = (f32x4){0.f, 0.f, 0.f, 0.f};

  const int*   kb   = kc  + (size_t)bg * KVc * Dc;
  const int*   vb   = vc  + (size_t)bg * KVc * Dc;
  const float* kscb = ksc + (size_t)bg * KVc;
  const float* kzrb = kzr + (size_t)bg * KVc;
  const float* vscb = vsc + (size_t)bg * KVc;
  const float* vzrb = vzr + (size_t)bg * KVc;

  // staging coords
  const int kt  = tid >> 3;                // K: token 0..31
  const int kd  = (tid & 7) << 4;          // K: d base 0,16,...,112 (halves)
  const int ksw = (kt & 7) << 3;           // K col swizzle (u16-index XOR)
  const int tq  = tid >> 5;                // V: token group 0..7
  const int dq  = (tid & 31) << 2;         // V: d base 0,4,...,124
  const int tb  = (tq << 2) ^ ((((dq >> 4) & 3)) << 3);  // swizzled col base

  i32x4 kp[4], vp[4];                      // K/V prefetch registers (one set)
  float ksA, kzA, vsA, vzA, ksB, kzB, vsB, vzB;  // loop-carried scale regs

  // ---- prologue: load+write tile 0; issue tile-1 K/V; load tile-0 scales --
  {
    const int* ksrc = kb + (size_t)(t_begin + kt) * Dc + kd;
#pragma unroll
    for (int i = 0; i < 4; ++i) kp[i] = ((const i32x4*)ksrc)[i];
#pragma unroll
    for (int i = 0; i < 4; ++i)
      vp[i] = *(const i32x4*)(vb + (size_t)(t_begin + (tq << 2) + i) * Dc + dq);

    ksA = kscb[t_begin + l15];      ksB = kscb[t_begin + 16 + l15];
    kzA = kzrb[t_begin + l15];      kzB = kzrb[t_begin + 16 + l15];
    vsA = vscb[t_begin + l15];      vsB = vscb[t_begin + 16 + l15];
    vzA = vzrb[t_begin + l15];      vzB = vzrb[t_begin + 16 + l15];

    i32x4 kA, kB;
    kA[0] = (int)pk1152(kp[0][0], kp[0][1]); kA[1] = (int)pk1152(kp[0][2], kp[0][3]);
    kA[2] = (int)pk1152(kp[1][0], kp[1][1]); kA[3] = (int)pk1152(kp[1][2], kp[1][3]);
    kB[0] = (int)pk1152(kp[2][0], kp[2][1]); kB[1] = (int)pk1152(kp[2][2], kp[2][3]);
    kB[2] = (int)pk1152(kp[3][0], kp[3][1]); kB[3] = (int)pk1152(kp[3][2], kp[3][3]);
    *(i32x4*)&Klds[kt][kd ^ ksw]       = kA;
    *(i32x4*)&Klds[kt][(kd + 8) ^ ksw] = kB;
#pragma unroll
    for (int j = 0; j < 4; ++j) {
      u32x2 pk;
      pk[0] = pk1152(vp[0][j], vp[1][j]);
      pk[1] = pk1152(vp[2][j], vp[3][j]);
      *(u32x2*)&Vlds[dq + j][tb] = pk;
    }
    if (nt > 1) {                          // tile-1 loads: in flight across
      const int* ksrc1 = kb + (size_t)(t_begin + 32 + kt) * Dc + kd;  // BAR now
#pragma unroll
      for (int i = 0; i < 4; ++i) kp[i] = ((const i32x4*)ksrc1)[i];
#pragma unroll
      for (int i = 0; i < 4; ++i)
        vp[i] = *(const i32x4*)(vb + (size_t)(t_begin + 32 + (tq << 2) + i) * Dc + dq);
    }
  }
  BAR();

  for (int it = 0; it < nt; ++it) {
    const int t0 = t_begin + (it << 5);

    // ---- compute tile from LDS (K/V loads for it+1 in flight) ----
    f32x4 scA = (f32x4){0.f, 0.f, 0.f, 0.f};
    f32x4 scB = (f32x4){0.f, 0.f, 0.f, 0.f};
#pragma unroll
    for (int ks = 0; ks < 4; ++ks) {
      f16x8 kfA = *(const f16x8*)
          &Klds[l15][(ks * 32 + (lg << 3)) ^ ((l15 & 7) << 3)];
      scA = __builtin_amdgcn_mfma_f32_16x16x32_f16(qa[ks], kfA, scA, 0, 0, 0);
    }
#pragma unroll
    for (int ks = 0; ks < 4; ++ks) {
      f16x8 kfB = *(const f16x8*)
          &Klds[16 + l15][(ks * 32 + (lg << 3)) ^ ((l15 & 7) << 3)];
      scB = __builtin_amdgcn_mfma_f32_16x16x32_f16(qa[ks], kfB, scB, 0, 0, 0);
    }

    float s8[2][4];
    const float sclA = ksA * QK_SCALE, kzpA = kzA + 1152.f;
    const float sclB = ksB * QK_SCALE, kzpB = kzB + 1152.f;
#pragma unroll
    for (int j = 0; j < 4; ++j) {
      s8[0][j] = sclA * (scA[j] - kzpA * qsumc[j]);
      s8[1][j] = sclB * (scB[j] - kzpB * qsumc[j]);
    }

    // one max update + rescale per 32-token tile
    float tm[4];
#pragma unroll
    for (int j = 0; j < 4; ++j) {
      tm[j] = fmaxf(s8[0][j], s8[1][j]);
      tm[j] = fmaxf(tm[j], __shfl_xor(tm[j], 1));
      tm[j] = fmaxf(tm[j], __shfl_xor(tm[j], 2));
      tm[j] = fmaxf(tm[j], __shfl_xor(tm[j], 4));
      tm[j] = fmaxf(tm[j], __shfl_xor(tm[j], 8));
    }
    bool need = false;
    float cf[4];
#pragma unroll
    for (int j = 0; j < 4; ++j) {
      float nm = fmaxf(m[j], tm[j]);
      cf[j] = exp2f(m[j] - nm);
      need = need || (tm[j] > m[j]);
      m[j] = nm;
    }
    if (__any(need)) {
#pragma unroll
      for (int j = 0; j < 4; ++j) { ell[j] *= cf[j]; corr[j] *= cf[j]; }
#pragma unroll
      for (int dt = 0; dt < 8; ++dt)
#pragma unroll
        for (int j = 0; j < 4; ++j) acc[dt][j] *= cf[j];
    }

    // P" = p*vs*1024 (fp16, out of subnormal range); corr uses ROUNDED P"
    const float vsA1k = vsA * 1024.f, vzpA = vzA + 1152.f;
    const float vsB1k = vsB * 1024.f, vzpB = vzB + 1152.f;
#pragma unroll
    for (int j = 0; j < 4; ++j) {
      float pA = exp2f(s8[0][j] - m[j]);
      float pB = exp2f(s8[1][j] - m[j]);
      ell[j] += pA + pB;
      union { _Float16 hh; unsigned short u; } ca, cb;
      ca.hh = (_Float16)(pA * vsA1k);
      cb.hh = (_Float16)(pB * vsB1k);
      corr[j] += (float)ca.hh * vzpA + (float)cb.hh * vzpB;
      Plds[wave][(lg << 2) + j][l15]      = ca.u;
      Plds[wave][(lg << 2) + j][16 + l15] = cb.u;
    }

    // PV for these 32 tokens
    f16x8 pa = *(const f16x8*)&Plds[wave][l15][lg << 3];
#pragma unroll
    for (int dt = 0; dt < 8; ++dt) {
      f16x8 vbf = *(const f16x8*)
          &Vlds[(dt << 4) + l15][(lg ^ (dt & 3)) << 3];
      acc[dt] = __builtin_amdgcn_mfma_f32_16x16x32_f16(pa, vbf, acc[dt], 0, 0, 0);
    }

    // ---- locked section: write it+1; issue it+2 K/V + it+1 scales ----
    if (it + 1 < nt) {
      BAR();                               // reads of old tile done (no vmcnt!)
      i32x4 kA, kB;                        // counted vmcnt wait for kp/vp here
      kA[0] = (int)pk1152(kp[0][0], kp[0][1]); kA[1] = (int)pk1152(kp[0][2], kp[0][3]);
      kA[2] = (int)pk1152(kp[1][0], kp[1][1]); kA[3] = (int)pk1152(kp[1][2], kp[1][3]);
      kB[0] = (int)pk1152(kp[2][0], kp[2][1]); kB[1] = (int)pk1152(kp[2][2], kp[2][3]);
      kB[2] = (int)pk1152(kp[3][0], kp[3][1]); kB[3] = (int)pk1152(kp[3][2], kp[3][3]);
      *(i32x4*)&Klds[kt][kd ^ ksw]       = kA;
      *(i32x4*)&Klds[kt][(kd + 8) ^ ksw] = kB;
#pragma unroll
      for (int j = 0; j < 4; ++j) {
        u32x2 pk;
        pk[0] = pk1152(vp[0][j], vp[1][j]);
        pk[1] = pk1152(vp[2][j], vp[3][j]);
        *(u32x2*)&Vlds[dq + j][tb] = pk;
      }
      // scales for tile it+1 (loop-carried; used in compute(it+1))
      {
        const int tn = t0 + 32;
        ksA = kscb[tn + l15];      ksB = kscb[tn + 16 + l15];
        kzA = kzrb[tn + l15];      kzB = kzrb[tn + 16 + l15];
        vsA = vscb[tn + l15];      vsB = vscb[tn + 16 + l15];
        vzA = vzrb[tn + l15];      vzB = vzrb[tn + 16 + l15];
      }
      if (it + 2 < nt) {                   // K/V for it+2: in flight across
        const int tn2 = t0 + 64;           // BAR + ALL of compute(it+1)
        const int* ksrc = kb + (size_t)(tn2 + kt) * Dc + kd;
#pragma unroll
        for (int i = 0; i < 4; ++i) kp[i] = ((const i32x4*)ksrc)[i];
#pragma unroll
        for (int i = 0; i < 4; ++i)
          vp[i] = *(const i32x4*)(vb + (size_t)(tn2 + (tq << 2) + i) * Dc + dq);
      }
      BAR();                               // writes visible (lgkmcnt only)
    }
  }

  // ---- final lane reductions over token slots ----
#pragma unroll
  for (int j = 0; j < 4; ++j) {
    ell[j] += __shfl_xor(ell[j], 1);  ell[j] += __shfl_xor(ell[j], 2);
    ell[j] += __shfl_xor(ell[j], 4);  ell[j] += __shfl_xor(ell[j], 8);
    corr[j] += __shfl_xor(corr[j], 1); corr[j] += __shfl_xor(corr[j], 2);
    corr[j] += __shfl_xor(corr[j], 4); corr[j] += __shfl_xor(corr[j], 8);
  }

  const size_t pbase = ((size_t)bg * nsplit + split) * 64;
  const float inv1k = 0.0009765625f;       // 1/1024 (undo P" scaling)
#pragma unroll
  for (int dt = 0; dt < 8; ++dt)
#pragma unroll
    for (int j = 0; j < 4; ++j) {
      int row = (wave << 4) + (lg << 2) + j;
      int d   = (dt << 4) + l15;
      ws_acc[(pbase + row) * Dc + d] = (acc[dt][j] - corr[j]) * inv1k;
    }
  if (l15 == 0) {
#pragma unroll
    for (int j = 0; j < 4; ++j) {
      int row = (wave << 4) + (lg << 2) + j;
      ws_m[pbase + row] = m[j];
      ws_l[pbase + row] = ell[j];
    }
  }
}

// ---------------------------------------------------------------------------
// Phase 2: flash-combine partials and normalize. One block per (bg,row).
// ---------------------------------------------------------------------------
__global__ __launch_bounds__(128) void attn_combine(
    const float* __restrict__ ws_acc, const float* __restrict__ ws_m,
    const float* __restrict__ ws_l, float* __restrict__ out, int nsplit)
{
  const int r   = blockIdx.x;      // 0 .. 32*64-1
  const int bg  = r >> 6;
  const int row = r & 63;
  const int d   = threadIdx.x;     // 0..127

  float M = -1e30f;
#pragma unroll 4
  for (int i = 0; i < nsplit; ++i)
    M = fmaxf(M, ws_m[((size_t)bg * nsplit + i) * 64 + row]);
  float L = 0.f, o = 0.f;
#pragma unroll 4
  for (int i = 0; i < nsplit; ++i) {
    size_t pb = ((size_t)bg * nsplit + i) * 64 + row;
    float w = exp2f(ws_m[pb] - M);
    L += ws_l[pb] * w;
    o += ws_acc[pb * Dc + d] * w;
  }
  const int b = bg >> 3, g = bg & 7;
  const int rep = row >> 4, qq = row & 15;
  out[(((size_t)(b * Hc + g * NREPc + rep)) * QLc + qq) * Dc + d] = o / L;
}

extern "C" void kernel_launch(void* const* d_in, const int* in_sizes, int n_in,
                              void* d_out, int out_size, void* d_ws,
                              size_t ws_size, hipStream_t stream) {
  const float* q   = (const float*)d_in[0];
  const int*   kc  = (const int*)d_in[1];   // int8 values promoted to int32
  const int*   vc  = (const int*)d_in[2];
  const float* ksc = (const float*)d_in[3];
  const float* kzr = (const float*)d_in[4];
  const float* vsc = (const float*)d_in[5];
  const float* vzr = (const float*)d_in[6];
  float* out = (float*)d_out;

  int nsplit = 64;                         // 2048 blocks; fallback if ws small
  while (nsplit > 1) {
    size_t need = (size_t)32 * nsplit * 64 * (Dc + 2) * sizeof(float);
    if (need <= ws_size) break;
    nsplit >>= 1;
  }
  float* ws_acc = (float*)d_ws;                             // [32,ns,64,128]
  float* ws_m   = ws_acc + (size_t)32 * nsplit * 64 * Dc;   // [32,ns,64]
  float* ws_l   = ws_m   + (size_t)32 * nsplit * 64;        // [32,ns,64]

  attn_partial<<<dim3(32 * nsplit), dim3(256), 0, stream>>>(
      q, kc, vc, ksc, kzr, vsc, vzr, ws_acc, ws_m, ws_l, nsplit);
  attn_combine<<<dim3(32 * 64), dim3(128), 0, stream>>>(
      ws_acc, ws_m, ws_l, out, nsplit);
}